// Round 9
// baseline (726.841 us; speedup 1.0000x reference)
//
#include <hip/hip_runtime.h>

typedef _Float16 f16;
typedef __attribute__((ext_vector_type(8))) _Float16 f16x8;
typedef __attribute__((ext_vector_type(4))) _Float16 f16x4;
typedef __attribute__((ext_vector_type(4))) float f32x4;

#define MFMA16(a, b, c) __builtin_amdgcn_mfma_f32_16x16x32_f16(a, b, c, 0, 0, 0)

#define SCALE_F 0.17677669529663687f
#define NHEAD 12
#define NTOK 49
#define NBW 2048
#define VTJ 56  // j-dim of transposed V buffers

#define SCHEDB() __builtin_amdgcn_sched_barrier(0)
#define WAITL0() asm volatile("s_waitcnt lgkmcnt(0)" ::: "memory")

// ---------------------------------------------------------------------------
// all four weight casts in one launch (f32 -> f16, x4 vectors)
// ---------------------------------------------------------------------------
__global__ void cast_weights(const float* __restrict__ wqkv, const float* __restrict__ wvse,
                             const float* __restrict__ wpse, const float* __restrict__ wpde,
                             f16* o_qkv, f16* o_vse, f16* o_pse, f16* o_pde) {
    int i = blockIdx.x * 256 + threadIdx.x;  // x4 groups; total 221184
    if (i >= 221184) return;
    const float* src;
    f16* dst;
    int off;
    if (i < 110592) { src = wqkv; dst = o_qkv; off = i; }
    else if (i < 147456) { src = wvse; dst = o_vse; off = i - 110592; }
    else if (i < 184320) { src = wpse; dst = o_pse; off = i - 147456; }
    else { src = wpde; dst = o_pde; off = i - 184320; }
    f32x4 v = ((const f32x4*)src)[off];
    f16x4 o;
#pragma unroll
    for (int e = 0; e < 4; ++e) o[e] = (f16)v[e];
    ((f16x4*)dst)[off] = o;
}

// ---------------------------------------------------------------------------
// precompute BM[w4][h][64][64] = rpb-bias + mask, padded with -1e30
// ---------------------------------------------------------------------------
__global__ void prep_bm(const float* __restrict__ rpb, const int* __restrict__ rel_idx,
                        const float* __restrict__ mask, float* __restrict__ bm) {
    int blk = blockIdx.x;  // w4*12 + h
    int w4 = blk / NHEAD, h = blk - w4 * NHEAD;
    for (int idx = threadIdx.x; idx < 4096; idx += 64) {
        int r = idx >> 6, c = idx & 63;
        float v = -1e30f;
        if (r < NTOK && c < NTOK)
            v = rpb[rel_idx[r * NTOK + c] * NHEAD + h] + mask[(w4 * NTOK + r) * NTOK + c];
        bm[(size_t)blk * 4096 + idx] = v;
    }
}

// ---------------------------------------------------------------------------
// GEMM: C[M][N] = A[M][K=384] @ B[N][K]^T + bias[N]
// 128x128 tile, BK=64, 256 threads (4 waves, 2x2), T1 XCD swizzle.
// R4-proven loop: sync -> stage -> sync -> compute. A_F32: A reg-staged f32
// with fused cast + swizzled ds_write; else A via global_load_lds.
// EPI (uniform per dispatch — no mixed-path register bloat):
//   0 = plain store to C (ldc)
//   1 = plain store to C (ldc) with cols<384 pre-scaled by SCALE_F (qk)
//   2 = all cols -> VT transposed scatter (v streams)
// ---------------------------------------------------------------------------
template <int EPI, bool A_F32, typename OUT_T>
__global__ __launch_bounds__(256) void gemm_bt(const void* __restrict__ Av, const f16* __restrict__ B,
                                               const float* __restrict__ bias, OUT_T* __restrict__ C,
                                               f16* __restrict__ VT, int ldc) {
    __shared__ __align__(16) f16 As[128 * 64];
    __shared__ __align__(16) f16 Bs[128 * 64];
    const int nwg = gridDim.x * gridDim.y;
    int wg = blockIdx.y * gridDim.x + blockIdx.x;
    wg = (wg & 7) * (nwg >> 3) + (wg >> 3);
    const int m0 = (wg / gridDim.x) * 128, n0 = (wg % gridDim.x) * 128;
    const int tid = threadIdx.x;
    const int w = tid >> 6, l = tid & 63;
    const int wm = w >> 1, wn = w & 1;
    const int lr = l & 15, lg = l >> 4;
    const int sp = l & 7;
    const int lrow = l >> 3;

    f32x4 acc[4][4] = {};

    for (int t = 0; t < 6; ++t) {
        __syncthreads();
        if constexpr (A_F32) {
            const float* A32 = (const float*)Av;
            f32x4 t0[4], t1[4];
#pragma unroll
            for (int it = 0; it < 4; ++it) {
                int row = w * 32 + it * 8 + lrow;
                const float* g = A32 + (size_t)(m0 + row) * 384 + t * 64 + sp * 8;
                t0[it] = *(const f32x4*)g;
                t1[it] = *(const f32x4*)(g + 4);
            }
#pragma unroll
            for (int it = 0; it < 4; ++it) {
                int row = w * 32 + it * 8 + lrow;
                f16x8 hx;
#pragma unroll
                for (int e = 0; e < 4; ++e) { hx[e] = (f16)t0[it][e]; hx[e + 4] = (f16)t1[it][e]; }
                *(f16x8*)(As + row * 64 + (sp ^ (row & 7)) * 8) = hx;
            }
#pragma unroll
            for (int it = 0; it < 4; ++it) {
                int row = w * 32 + it * 8 + lrow;
                int gchunk = sp ^ (row & 7);
                const f16* gB = B + (size_t)(n0 + row) * 384 + t * 64 + gchunk * 8;
                f16* lB = Bs + (w * 32 + it * 8) * 64;  // wave-uniform; HW adds lane*16B
                __builtin_amdgcn_global_load_lds((const __attribute__((address_space(1))) void*)gB,
                                                 (__attribute__((address_space(3))) void*)lB, 16, 0, 0);
            }
        } else {
            const f16* A16 = (const f16*)Av;
#pragma unroll
            for (int it = 0; it < 4; ++it) {
                int row = w * 32 + it * 8 + lrow;
                int gchunk = sp ^ (row & 7);
                const f16* gA = A16 + (size_t)(m0 + row) * 384 + t * 64 + gchunk * 8;
                const f16* gB = B + (size_t)(n0 + row) * 384 + t * 64 + gchunk * 8;
                f16* lA = As + (w * 32 + it * 8) * 64;
                f16* lB = Bs + (w * 32 + it * 8) * 64;
                __builtin_amdgcn_global_load_lds((const __attribute__((address_space(1))) void*)gA,
                                                 (__attribute__((address_space(3))) void*)lA, 16, 0, 0);
                __builtin_amdgcn_global_load_lds((const __attribute__((address_space(1))) void*)gB,
                                                 (__attribute__((address_space(3))) void*)lB, 16, 0, 0);
            }
        }
        __syncthreads();
#pragma unroll
        for (int ks = 0; ks < 2; ++ks) {
            f16x8 af[4], bfr[4];
#pragma unroll
            for (int mi = 0; mi < 4; ++mi) {
                int r = 64 * wm + 16 * mi + lr;
                int chunk = (lg + 4 * ks) ^ (r & 7);
                af[mi] = *(const f16x8*)(As + r * 64 + chunk * 8);
            }
#pragma unroll
            for (int ni = 0; ni < 4; ++ni) {
                int r = 64 * wn + 16 * ni + lr;
                int chunk = (lg + 4 * ks) ^ (r & 7);
                bfr[ni] = *(const f16x8*)(Bs + r * 64 + chunk * 8);
            }
            __builtin_amdgcn_s_setprio(1);
#pragma unroll
            for (int mi = 0; mi < 4; ++mi)
#pragma unroll
                for (int ni = 0; ni < 4; ++ni)
                    acc[mi][ni] = MFMA16(af[mi], bfr[ni], acc[mi][ni]);
            __builtin_amdgcn_s_setprio(0);
        }
    }

    // epilogue: C/D layout col=lane&15, row=(lane>>4)*4+reg [m89]
#pragma unroll
    for (int mi = 0; mi < 4; ++mi) {
#pragma unroll
        for (int ni = 0; ni < 4; ++ni) {
            int col = n0 + 64 * wn + 16 * ni + lr;
            float bv = bias[col];
#pragma unroll
            for (int reg = 0; reg < 4; ++reg) {
                int row = m0 + 64 * wm + 16 * mi + 4 * lg + reg;
                float v = acc[mi][ni][reg] + bv;
                if constexpr (EPI == 0) {
                    C[(size_t)row * ldc + col] = (OUT_T)v;
                } else if constexpr (EPI == 1) {
                    if (col < 384) v *= SCALE_F;  // fold softmax scale into Q
                    C[(size_t)row * ldc + col] = (OUT_T)v;
                } else {
                    int b = row / 49, j = row - b * 49;
                    VT[((size_t)b * NHEAD + (col >> 5)) * (32 * VTJ) + (col & 31) * VTJ + j] = (f16)v;
                }
            }
        }
    }
}

// ---------------------------------------------------------------------------
// fused attention: 128 threads = 2 independent waves, each owns one (window,
// head). QK^T from qk_h (stride 768, Q pre-scaled), V fragments via 16B
// vector loads from transposed Vt buffers (T14-prefetched under softmax),
// wave-parallel softmax, P through wave-private XOR-swizzled LDS.
// ---------------------------------------------------------------------------
__global__ __launch_bounds__(128) void attn_kernel(const f16* __restrict__ qk,
                                                   const f16* __restrict__ vse_t,
                                                   const f16* __restrict__ vde_t,
                                                   const float* __restrict__ bm_all,
                                                   f16* __restrict__ att_se, f16* __restrict__ att_de) {
    __shared__ __align__(16) f16 Ps[2][64 * 64];  // per-wave P, swizzled

    const int wv = threadIdx.x >> 6;
    const int l = threadIdx.x & 63;
    const int bh = blockIdx.x * 2 + wv;
    const int b = bh / NHEAD, h = bh - b * NHEAD;
    const int lr = l & 15, lg = l >> 4;
    const size_t wbase = (size_t)b * NTOK;
    f16* P = Ps[wv];

    f16x8 qa[4], kb[4];
#pragma unroll
    for (int mi = 0; mi < 4; ++mi)
        qa[mi] = *(const f16x8*)(qk + (wbase + 16 * mi + lr) * 768 + h * 32 + lg * 8);
#pragma unroll
    for (int ni = 0; ni < 4; ++ni)
        kb[ni] = *(const f16x8*)(qk + (wbase + 16 * ni + lr) * 768 + 384 + h * 32 + lg * 8);

    const f32x4 zero4 = {0.f, 0.f, 0.f, 0.f};
    f32x4 S[4][4];
    __builtin_amdgcn_s_setprio(1);
#pragma unroll
    for (int mi = 0; mi < 4; ++mi)
#pragma unroll
        for (int ni = 0; ni < 4; ++ni)
            S[mi][ni] = MFMA16(qa[mi], kb[ni], zero4);
    __builtin_amdgcn_s_setprio(0);

    // T14: prefetch V fragments; complete under the softmax. j>=49 -> P=0.
    f16x8 vbr[2][2][2];  // [stream][ks][ni]
#pragma unroll
    for (int s = 0; s < 2; ++s) {
        const f16* vt = (s ? vde_t : vse_t) + (size_t)bh * (32 * VTJ);
#pragma unroll
        for (int ks = 0; ks < 2; ++ks)
#pragma unroll
            for (int ni = 0; ni < 2; ++ni) {
                int j0 = 8 * lg + 32 * ks;
                if (j0 == 56) j0 = 48;  // VTJ=56: top slot re-reads j=48 block (P=0 there)
                vbr[s][ks][ni] = *(const f16x8*)(vt + (16 * ni + lr) * VTJ + j0);
            }
    }

    const float* bmp = bm_all + (size_t)((b & 3) * NHEAD + h) * 4096;
#pragma unroll
    for (int mi = 0; mi < 4; ++mi) {
#pragma unroll
        for (int reg = 0; reg < 4; ++reg) {
            int r = 16 * mi + 4 * lg + reg;
            float v[4];
#pragma unroll
            for (int ni = 0; ni < 4; ++ni)
                v[ni] = S[mi][ni][reg] + bmp[(r << 6) + 16 * ni + lr];
            float mx = fmaxf(fmaxf(v[0], v[1]), fmaxf(v[2], v[3]));
#pragma unroll
            for (int off = 1; off < 16; off <<= 1) mx = fmaxf(mx, __shfl_xor(mx, off));
            float e[4];
            float sm = 0.f;
#pragma unroll
            for (int ni = 0; ni < 4; ++ni) {
                e[ni] = __expf(v[ni] - mx);
                sm += e[ni];
            }
#pragma unroll
            for (int off = 1; off < 16; off <<= 1) sm += __shfl_xor(sm, off);
            float inv = 1.f / sm;
#pragma unroll
            for (int ni = 0; ni < 4; ++ni)
                P[(r << 6) + ((16 * ni + lr) ^ ((r & 7) << 3))] = (f16)(e[ni] * inv);
        }
    }
    WAITL0();  // wave-private P: per-wave LDS ordering is enough
    SCHEDB();

#pragma unroll
    for (int s = 0; s < 2; ++s) {
        f32x4 o[4][2] = {};
#pragma unroll
        for (int ks = 0; ks < 2; ++ks) {
            f16x8 pa[4];
#pragma unroll
            for (int mi = 0; mi < 4; ++mi) {
                int r = 16 * mi + lr;
                pa[mi] = *(const f16x8*)(P + (r << 6) + ((8 * lg + 32 * ks) ^ ((r & 7) << 3)));
            }
            __builtin_amdgcn_s_setprio(1);
#pragma unroll
            for (int ni = 0; ni < 2; ++ni)
#pragma unroll
                for (int mi = 0; mi < 4; ++mi) o[mi][ni] = MFMA16(pa[mi], vbr[s][ks][ni], o[mi][ni]);
            __builtin_amdgcn_s_setprio(0);
        }
        f16* dst = s ? att_de : att_se;
#pragma unroll
        for (int mi = 0; mi < 4; ++mi) {
#pragma unroll
            for (int reg = 0; reg < 4; ++reg) {
                int r = 16 * mi + 4 * lg + reg;
                if (r < NTOK) {
#pragma unroll
                    for (int ni = 0; ni < 2; ++ni)
                        dst[(wbase + r) * 384 + h * 32 + 16 * ni + lr] = (f16)o[mi][ni][reg];
                }
            }
        }
    }
}

// ---------------------------------------------------------------------------
extern "C" void kernel_launch(void* const* d_in, const int* in_sizes, int n_in,
                              void* d_out, int out_size, void* d_ws, size_t ws_size,
                              hipStream_t stream) {
    const float* se = (const float*)d_in[0];
    const float* de = (const float*)d_in[1];
    const float* mask = (const float*)d_in[2];
    const float* w_v_se = (const float*)d_in[3];
    const float* b_v_se = (const float*)d_in[4];
    const float* w_qkv = (const float*)d_in[5];
    const float* b_qkv = (const float*)d_in[6];
    const float* w_proj_se = (const float*)d_in[7];
    const float* b_proj_se = (const float*)d_in[8];
    const float* w_proj_de = (const float*)d_in[9];
    const float* b_proj_de = (const float*)d_in[10];
    const float* rpb = (const float*)d_in[11];
    const int* rel_idx = (const int*)d_in[12];

    const size_t SE_ELEMS = (size_t)NBW * NTOK * 384;  // 38,535,168

    char* ws = (char*)d_ws;
    f16* att_se = (f16*)(ws);                   // (100352, 384)
    f16* att_de = (f16*)(ws + 77070336);        // (100352, 384)
    f16* qk_h   = (f16*)(ws + 154140672);       // (100352, 768)
    f16* vse_t  = (f16*)(ws + 308281344);       // (24576, 32, 56)
    f16* vde_t  = (f16*)(ws + 396361728);       // (24576, 32, 56)
    f16* wqkv_h = (f16*)(ws + 484442112);
    f16* wvse_h = (f16*)(ws + 485326848);
    f16* wpse_h = (f16*)(ws + 485621760);
    f16* wpde_h = (f16*)(ws + 485916672);
    float* bm   = (float*)(ws + 486211584);

    cast_weights<<<864, 256, 0, stream>>>(w_qkv, w_v_se, w_proj_se, w_proj_de,
                                          wqkv_h, wvse_h, wpse_h, wpde_h);
    prep_bm<<<48, 64, 0, stream>>>(rpb, rel_idx, mask, bm);

    // qk = de @ w_qkv[0:768]^T + b (Q pre-scaled) -> qk_h, plain epilogue
    gemm_bt<1, true, f16><<<dim3(6, 784), 256, 0, stream>>>((const void*)de, wqkv_h, b_qkv,
                                                            qk_h, nullptr, 768);
    // v_de = de @ w_qkv[768:]^T + b -> vde_t transposed (uniform scatter epilogue)
    gemm_bt<2, true, f16><<<dim3(3, 784), 256, 0, stream>>>((const void*)de, wqkv_h + 768 * 384,
                                                            b_qkv + 768, (f16*)nullptr, vde_t, 0);
    // v_se = se @ w_v_se^T + b -> vse_t transposed
    gemm_bt<2, true, f16><<<dim3(3, 784), 256, 0, stream>>>((const void*)se, wvse_h, b_v_se,
                                                            (f16*)nullptr, vse_t, 0);

    // attention: 2 (window,head) pairs per block
    attn_kernel<<<NBW * NHEAD / 2, 128, 0, stream>>>(qk_h, vse_t, vde_t, bm, att_se, att_de);

    // projections straight into d_out (f32); A is f16 -> global_load_lds path
    gemm_bt<0, false, float><<<dim3(3, 784), 256, 0, stream>>>((const void*)att_se, wpse_h, b_proj_se,
                                                               (float*)d_out, nullptr, 384);
    gemm_bt<0, false, float><<<dim3(3, 784), 256, 0, stream>>>((const void*)att_de, wpde_h, b_proj_de,
                                                               (float*)d_out + SE_ELEMS, nullptr, 384);
}

// Round 11
// 722.621 us; speedup vs baseline: 1.0058x; 1.0058x over previous
//
#include <hip/hip_runtime.h>

typedef _Float16 f16;
typedef __attribute__((ext_vector_type(8))) _Float16 f16x8;
typedef __attribute__((ext_vector_type(4))) _Float16 f16x4;
typedef __attribute__((ext_vector_type(4))) float f32x4;

#define MFMA16(a, b, c) __builtin_amdgcn_mfma_f32_16x16x32_f16(a, b, c, 0, 0, 0)

#define SCALE_F 0.17677669529663687f
#define NHEAD 12
#define NTOK 49
#define NBW 2048

#define SCHEDB() __builtin_amdgcn_sched_barrier(0)
#define WAITL0() asm volatile("s_waitcnt lgkmcnt(0)" ::: "memory")

// ---------------------------------------------------------------------------
// all four weight casts in one launch (f32 -> f16, x4 vectors)
// ---------------------------------------------------------------------------
__global__ void cast_weights(const float* __restrict__ wqkv, const float* __restrict__ wvse,
                             const float* __restrict__ wpse, const float* __restrict__ wpde,
                             f16* o_qkv, f16* o_vse, f16* o_pse, f16* o_pde) {
    int i = blockIdx.x * 256 + threadIdx.x;  // x4 groups; total 221184
    if (i >= 221184) return;
    const float* src;
    f16* dst;
    int off;
    if (i < 110592) { src = wqkv; dst = o_qkv; off = i; }
    else if (i < 147456) { src = wvse; dst = o_vse; off = i - 110592; }
    else if (i < 184320) { src = wpse; dst = o_pse; off = i - 147456; }
    else { src = wpde; dst = o_pde; off = i - 184320; }
    f32x4 v = ((const f32x4*)src)[off];
    f16x4 o;
#pragma unroll
    for (int e = 0; e < 4; ++e) o[e] = (f16)v[e];
    ((f16x4*)dst)[off] = o;
}

// ---------------------------------------------------------------------------
// precompute BM[w4][h][64][64] = rpb-bias + mask, padded with -1e30
// ---------------------------------------------------------------------------
__global__ void prep_bm(const float* __restrict__ rpb, const int* __restrict__ rel_idx,
                        const float* __restrict__ mask, float* __restrict__ bm) {
    int blk = blockIdx.x;  // w4*12 + h
    int w4 = blk / NHEAD, h = blk - w4 * NHEAD;
    for (int idx = threadIdx.x; idx < 4096; idx += 64) {
        int r = idx >> 6, c = idx & 63;
        float v = -1e30f;
        if (r < NTOK && c < NTOK)
            v = rpb[rel_idx[r * NTOK + c] * NHEAD + h] + mask[(w4 * NTOK + r) * NTOK + c];
        bm[(size_t)blk * 4096 + idx] = v;
    }
}

// ---------------------------------------------------------------------------
// GEMM: C[M][N] = A[M][K=384] @ B[N][K]^T + bias[N]
// Tile 256M x 64N, BK=64, 512 threads (8 waves, each 32x64: acc 2x4 frags =
// 32 AGPR). N-tiles fast in grid: A rows are loaded+cast EXACTLY ONCE; tiny
// B is the L2-hot re-read operand. R4-proven 2-barrier loop. A_F32: A
// reg-staged f32 + fused cast + XOR-swizzled ds_write (load chunk sp^(r&7),
// store AT position sp — position p holds global chunk p^(r&7), matching the
// global_load_lds pre-swizzled-source convention). Else A via global_load_lds.
// T1 bijective XCD swizzle (grids divisible by 8). Plain epilogue.
// ---------------------------------------------------------------------------
template <bool A_F32, typename OUT_T>
__global__ __launch_bounds__(512, 4) void gemm256(const void* __restrict__ Av, const f16* __restrict__ B,
                                                  const float* __restrict__ bias, OUT_T* __restrict__ C,
                                                  int ldc) {
    __shared__ __align__(16) f16 As[256 * 64];
    __shared__ __align__(16) f16 Bs[64 * 64];
    const int nwg = gridDim.x * gridDim.y;
    int wg = blockIdx.y * gridDim.x + blockIdx.x;
    wg = (wg & 7) * (nwg >> 3) + (wg >> 3);
    const int m0 = (wg / gridDim.x) * 256, n0 = (wg % gridDim.x) * 64;
    const int tid = threadIdx.x;
    const int w = tid >> 6, l = tid & 63;
    const int lr = l & 15, lg = l >> 4;
    const int sp = tid & 7;
    const int lrow = tid >> 3;  // 0..63

    f32x4 acc[2][4] = {};

    for (int t = 0; t < 6; ++t) {
        __syncthreads();
        if constexpr (A_F32) {
            const float* A32 = (const float*)Av;
#pragma unroll
            for (int it = 0; it < 4; ++it) {
                int row = it * 64 + lrow;
                int c = sp ^ (row & 7);                      // global chunk to fetch
                const float* g = A32 + (size_t)(m0 + row) * 384 + t * 64 + c * 8;
                f32x4 t0 = *(const f32x4*)g;
                f32x4 t1 = *(const f32x4*)(g + 4);
                f16x8 hx;
#pragma unroll
                for (int e = 0; e < 4; ++e) { hx[e] = (f16)t0[e]; hx[e + 4] = (f16)t1[e]; }
                *(f16x8*)(As + row * 64 + sp * 8) = hx;      // store at position sp (swizzle!)
            }
        } else {
            const f16* A16 = (const f16*)Av;
#pragma unroll
            for (int it = 0; it < 4; ++it) {
                int row0 = it * 64 + w * 8;                 // wave-uniform LDS base
                int row = row0 + (l >> 3);
                int c = (l & 7) ^ (row & 7);                // pre-swizzled source
                const f16* gA = A16 + (size_t)(m0 + row) * 384 + t * 64 + c * 8;
                f16* lA = As + row0 * 64;
                __builtin_amdgcn_global_load_lds((const __attribute__((address_space(1))) void*)gA,
                                                 (__attribute__((address_space(3))) void*)lA, 16, 0, 0);
            }
        }
        {
            int row0 = w * 8;                               // B: 64 rows, 1 issue/wave
            int row = row0 + (l >> 3);
            int c = (l & 7) ^ (row & 7);
            const f16* gB = B + (size_t)(n0 + row) * 384 + t * 64 + c * 8;
            f16* lB = Bs + row0 * 64;
            __builtin_amdgcn_global_load_lds((const __attribute__((address_space(1))) void*)gB,
                                             (__attribute__((address_space(3))) void*)lB, 16, 0, 0);
        }
        __syncthreads();
#pragma unroll
        for (int ks = 0; ks < 2; ++ks) {
            f16x8 af[2], bfr[4];
#pragma unroll
            for (int mi = 0; mi < 2; ++mi) {
                int r = w * 32 + mi * 16 + lr;
                int c = (ks * 4 + lg) ^ (r & 7);
                af[mi] = *(const f16x8*)(As + r * 64 + c * 8);
            }
#pragma unroll
            for (int ni = 0; ni < 4; ++ni) {
                int r = ni * 16 + lr;
                int c = (ks * 4 + lg) ^ (r & 7);
                bfr[ni] = *(const f16x8*)(Bs + r * 64 + c * 8);
            }
            __builtin_amdgcn_s_setprio(1);
#pragma unroll
            for (int mi = 0; mi < 2; ++mi)
#pragma unroll
                for (int ni = 0; ni < 4; ++ni)
                    acc[mi][ni] = MFMA16(af[mi], bfr[ni], acc[mi][ni]);
            __builtin_amdgcn_s_setprio(0);
        }
    }

    // epilogue: C/D layout col=lane&15, row=(lane>>4)*4+reg [m89]
#pragma unroll
    for (int mi = 0; mi < 2; ++mi) {
#pragma unroll
        for (int ni = 0; ni < 4; ++ni) {
            int col = n0 + ni * 16 + lr;
            float bv = bias[col];
#pragma unroll
            for (int reg = 0; reg < 4; ++reg) {
                int row = m0 + w * 32 + mi * 16 + 4 * lg + reg;
                C[(size_t)row * ldc + col] = (OUT_T)(acc[mi][ni][reg] + bv);
            }
        }
    }
}

// ---------------------------------------------------------------------------
// fused attention (R4-proven): 128 threads = 2 independent waves, each owns
// one (window,head). QK^T via MFMA from interleaved qkv, V fragments
// prefetched into registers right after QK^T (T14, hides under softmax),
// wave-parallel softmax, P through wave-private XOR-swizzled LDS, MFMA PV.
// Over-reads (rows past last window / j>=49) stay inside ws; P=0 kills them.
// ---------------------------------------------------------------------------
__global__ __launch_bounds__(128) void attn_kernel(const f16* __restrict__ qkv,
                                                   const f16* __restrict__ vse,
                                                   const float* __restrict__ bm_all,
                                                   f16* __restrict__ att_se, f16* __restrict__ att_de) {
    __shared__ __align__(16) f16 Ps[2][64 * 64];  // per-wave P, swizzled

    const int wv = threadIdx.x >> 6;
    const int l = threadIdx.x & 63;
    const int bh = blockIdx.x * 2 + wv;
    const int b = bh / NHEAD, h = bh - b * NHEAD;
    const int lr = l & 15, lg = l >> 4;
    const size_t wbase = (size_t)b * NTOK;
    f16* P = Ps[wv];

    f16x8 qa[4], kb[4];
#pragma unroll
    for (int mi = 0; mi < 4; ++mi)
        qa[mi] = *(const f16x8*)(qkv + (wbase + 16 * mi + lr) * 1152 + h * 32 + lg * 8);
#pragma unroll
    for (int ni = 0; ni < 4; ++ni)
        kb[ni] = *(const f16x8*)(qkv + (wbase + 16 * ni + lr) * 1152 + 384 + h * 32 + lg * 8);

    const f32x4 zero4 = {0.f, 0.f, 0.f, 0.f};
    f32x4 S[4][4];
    __builtin_amdgcn_s_setprio(1);
#pragma unroll
    for (int mi = 0; mi < 4; ++mi)
#pragma unroll
        for (int ni = 0; ni < 4; ++ni)
            S[mi][ni] = MFMA16(qa[mi], kb[ni], zero4);
    __builtin_amdgcn_s_setprio(0);

    // T14: issue all V-fragment gathers now; they complete under the softmax
    f16x8 vbr[2][2][2];  // [stream][ks][ni]
#pragma unroll
    for (int s = 0; s < 2; ++s) {
        const f16* vbase = s ? (qkv + wbase * 1152 + 768 + h * 32) : (vse + wbase * 384 + h * 32);
        const int RS = s ? 1152 : 384;
#pragma unroll
        for (int ks = 0; ks < 2; ++ks)
#pragma unroll
            for (int ni = 0; ni < 2; ++ni) {
                const f16* p = vbase + (size_t)(8 * lg + 32 * ks) * RS + 16 * ni + lr;
#pragma unroll
                for (int e = 0; e < 8; ++e) vbr[s][ks][ni][e] = p[(size_t)e * RS];
            }
    }

    const float* bmp = bm_all + (size_t)((b & 3) * NHEAD + h) * 4096;
#pragma unroll
    for (int mi = 0; mi < 4; ++mi) {
#pragma unroll
        for (int reg = 0; reg < 4; ++reg) {
            int r = 16 * mi + 4 * lg + reg;
            float v[4];
#pragma unroll
            for (int ni = 0; ni < 4; ++ni)
                v[ni] = S[mi][ni][reg] * SCALE_F + bmp[(r << 6) + 16 * ni + lr];
            float mx = fmaxf(fmaxf(v[0], v[1]), fmaxf(v[2], v[3]));
#pragma unroll
            for (int off = 1; off < 16; off <<= 1) mx = fmaxf(mx, __shfl_xor(mx, off));
            float e[4];
            float sm = 0.f;
#pragma unroll
            for (int ni = 0; ni < 4; ++ni) {
                e[ni] = __expf(v[ni] - mx);
                sm += e[ni];
            }
#pragma unroll
            for (int off = 1; off < 16; off <<= 1) sm += __shfl_xor(sm, off);
            float inv = 1.f / sm;
#pragma unroll
            for (int ni = 0; ni < 4; ++ni)
                P[(r << 6) + ((16 * ni + lr) ^ ((r & 7) << 3))] = (f16)(e[ni] * inv);
        }
    }
    WAITL0();  // wave-private P: per-wave LDS ordering is enough
    SCHEDB();

#pragma unroll
    for (int s = 0; s < 2; ++s) {
        f32x4 o[4][2] = {};
#pragma unroll
        for (int ks = 0; ks < 2; ++ks) {
            f16x8 pa[4];
#pragma unroll
            for (int mi = 0; mi < 4; ++mi) {
                int r = 16 * mi + lr;
                pa[mi] = *(const f16x8*)(P + (r << 6) + ((8 * lg + 32 * ks) ^ ((r & 7) << 3)));
            }
            __builtin_amdgcn_s_setprio(1);
#pragma unroll
            for (int ni = 0; ni < 2; ++ni)
#pragma unroll
                for (int mi = 0; mi < 4; ++mi) o[mi][ni] = MFMA16(pa[mi], vbr[s][ks][ni], o[mi][ni]);
            __builtin_amdgcn_s_setprio(0);
        }
        f16* dst = s ? att_de : att_se;
#pragma unroll
        for (int mi = 0; mi < 4; ++mi) {
#pragma unroll
            for (int reg = 0; reg < 4; ++reg) {
                int r = 16 * mi + 4 * lg + reg;
                if (r < NTOK) {
#pragma unroll
                    for (int ni = 0; ni < 2; ++ni)
                        dst[(wbase + r) * 384 + h * 32 + 16 * ni + lr] = (f16)o[mi][ni][reg];
                }
            }
        }
    }
}

// ---------------------------------------------------------------------------
extern "C" void kernel_launch(void* const* d_in, const int* in_sizes, int n_in,
                              void* d_out, int out_size, void* d_ws, size_t ws_size,
                              hipStream_t stream) {
    const float* se = (const float*)d_in[0];
    const float* de = (const float*)d_in[1];
    const float* mask = (const float*)d_in[2];
    const float* w_v_se = (const float*)d_in[3];
    const float* b_v_se = (const float*)d_in[4];
    const float* w_qkv = (const float*)d_in[5];
    const float* b_qkv = (const float*)d_in[6];
    const float* w_proj_se = (const float*)d_in[7];
    const float* b_proj_se = (const float*)d_in[8];
    const float* w_proj_de = (const float*)d_in[9];
    const float* b_proj_de = (const float*)d_in[10];
    const float* rpb = (const float*)d_in[11];
    const int* rel_idx = (const int*)d_in[12];

    const size_t SE_ELEMS = (size_t)NBW * NTOK * 384;  // 38,535,168

    char* ws = (char*)d_ws;
    f16* att_se = (f16*)(ws);                   // (100352, 384)
    f16* att_de = (f16*)(ws + 77070336);        // (100352, 384)
    f16* qkv_h  = (f16*)(ws + 154140672);       // (100352, 1152)
    f16* vse_h  = (f16*)(ws + 385351680);       // (100352, 384)
    f16* wqkv_h = (f16*)(ws + 462422016);
    f16* wvse_h = (f16*)(ws + 463306752);
    f16* wpse_h = (f16*)(ws + 463601664);
    f16* wpde_h = (f16*)(ws + 463896576);
    float* bm   = (float*)(ws + 464191488);

    cast_weights<<<864, 256, 0, stream>>>(w_qkv, w_v_se, w_proj_se, w_proj_de,
                                          wqkv_h, wvse_h, wpse_h, wpde_h);
    prep_bm<<<48, 64, 0, stream>>>(rpb, rel_idx, mask, bm);

    // qkv = de @ w_qkv^T + b   (N=1152: 18 n-tiles x 392 m-tiles; A cast once)
    gemm256<true, f16><<<dim3(18, 392), 512, 0, stream>>>((const void*)de, wqkv_h, b_qkv, qkv_h, 1152);
    // v_se = se @ w_v_se^T + b (N=384: 6 n-tiles)
    gemm256<true, f16><<<dim3(6, 392), 512, 0, stream>>>((const void*)se, wvse_h, b_v_se, vse_h, 384);

    // attention: 2 (window,head) pairs per block
    attn_kernel<<<NBW * NHEAD / 2, 128, 0, stream>>>(qkv_h, vse_h, bm, att_se, att_de);

    // projections straight into d_out (f32); A is f16 -> global_load_lds path
    gemm256<false, float><<<dim3(6, 392), 512, 0, stream>>>((const void*)att_se, wpse_h, b_proj_se,
                                                            (float*)d_out, 384);
    gemm256<false, float><<<dim3(6, 392), 512, 0, stream>>>((const void*)att_de, wpde_h, b_proj_de,
                                                            (float*)d_out + SE_ELEMS, 384);
}

// Round 12
// 644.162 us; speedup vs baseline: 1.1284x; 1.1218x over previous
//
#include <hip/hip_runtime.h>

typedef _Float16 f16;
typedef __attribute__((ext_vector_type(8))) _Float16 f16x8;
typedef __attribute__((ext_vector_type(4))) _Float16 f16x4;
typedef __attribute__((ext_vector_type(4))) float f32x4;

#define MFMA16(a, b, c) __builtin_amdgcn_mfma_f32_16x16x32_f16(a, b, c, 0, 0, 0)

#define SCALE_F 0.17677669529663687f
#define NHEAD 12
#define NTOK 49
#define NBW 2048

#define SCHEDB() __builtin_amdgcn_sched_barrier(0)
#define WAITL0() asm volatile("s_waitcnt lgkmcnt(0)" ::: "memory")

// ---------------------------------------------------------------------------
// all four weight casts in one launch (f32 -> f16, x4 vectors)
// ---------------------------------------------------------------------------
__global__ void cast_weights(const float* __restrict__ wqkv, const float* __restrict__ wvse,
                             const float* __restrict__ wpse, const float* __restrict__ wpde,
                             f16* o_qkv, f16* o_vse, f16* o_pse, f16* o_pde) {
    int i = blockIdx.x * 256 + threadIdx.x;  // x4 groups; total 221184
    if (i >= 221184) return;
    const float* src;
    f16* dst;
    int off;
    if (i < 110592) { src = wqkv; dst = o_qkv; off = i; }
    else if (i < 147456) { src = wvse; dst = o_vse; off = i - 110592; }
    else if (i < 184320) { src = wpse; dst = o_pse; off = i - 147456; }
    else { src = wpde; dst = o_pde; off = i - 184320; }
    f32x4 v = ((const f32x4*)src)[off];
    f16x4 o;
#pragma unroll
    for (int e = 0; e < 4; ++e) o[e] = (f16)v[e];
    ((f16x4*)dst)[off] = o;
}

// ---------------------------------------------------------------------------
// precompute BM[w4][h][64][64] = rpb-bias + mask, padded with -1e30
// ---------------------------------------------------------------------------
__global__ void prep_bm(const float* __restrict__ rpb, const int* __restrict__ rel_idx,
                        const float* __restrict__ mask, float* __restrict__ bm) {
    int blk = blockIdx.x;  // w4*12 + h
    int w4 = blk / NHEAD, h = blk - w4 * NHEAD;
    for (int idx = threadIdx.x; idx < 4096; idx += 64) {
        int r = idx >> 6, c = idx & 63;
        float v = -1e30f;
        if (r < NTOK && c < NTOK)
            v = rpb[rel_idx[r * NTOK + c] * NHEAD + h] + mask[(w4 * NTOK + r) * NTOK + c];
        bm[(size_t)blk * 4096 + idx] = v;
    }
}

// ---------------------------------------------------------------------------
// GEMM (verbatim R4, the measured-best structure on this shape):
// C[M][N] = A[M][K] @ B[N][K]^T + bias[N]
// 128x128 tile, BK=64, 256 threads, T1 XCD swizzle, 2-barrier loop.
// A_F32: A reg-staged f32 + fused cast + swizzled ds_write; else A via
// global_load_lds with pre-swizzled source. B via global_load_lds.
// ---------------------------------------------------------------------------
template <typename OUT_T, bool A_F32>
__global__ __launch_bounds__(256) void gemm_bt(const void* __restrict__ Av, const f16* __restrict__ B,
                                               const float* __restrict__ bias, OUT_T* __restrict__ C,
                                               int M, int N, int K) {
    __shared__ __align__(16) f16 As[128 * 64];
    __shared__ __align__(16) f16 Bs[128 * 64];
    const int nwg = gridDim.x * gridDim.y;
    int wg = blockIdx.y * gridDim.x + blockIdx.x;
    wg = (wg & 7) * (nwg >> 3) + (wg >> 3);
    const int m0 = (wg / gridDim.x) * 128, n0 = (wg % gridDim.x) * 128;
    const int tid = threadIdx.x;
    const int w = tid >> 6, l = tid & 63;
    const int wm = w >> 1, wn = w & 1;
    const int lr = l & 15, lg = l >> 4;
    const int sp = l & 7;

    f32x4 acc[4][4] = {};

    for (int k0 = 0; k0 < K; k0 += 64) {
        __syncthreads();
        if constexpr (A_F32) {
            const float* A32 = (const float*)Av;
            f32x4 t0[4], t1[4];
#pragma unroll
            for (int it = 0; it < 4; ++it) {
                int row = w * 32 + it * 8 + (l >> 3);
                const float* g = A32 + (size_t)(m0 + row) * K + k0 + sp * 8;
                t0[it] = *(const f32x4*)g;
                t1[it] = *(const f32x4*)(g + 4);
            }
#pragma unroll
            for (int it = 0; it < 4; ++it) {
                int row = w * 32 + it * 8 + (l >> 3);
                f16x8 hx;
#pragma unroll
                for (int e = 0; e < 4; ++e) {
                    hx[e] = (f16)t0[it][e];
                    hx[e + 4] = (f16)t1[it][e];
                }
                *(f16x8*)(As + row * 64 + (sp ^ (row & 7)) * 8) = hx;
            }
#pragma unroll
            for (int it = 0; it < 4; ++it) {
                int row = w * 32 + it * 8 + (l >> 3);
                int gchunk = sp ^ (row & 7);
                const f16* gB = B + (size_t)(n0 + row) * K + k0 + gchunk * 8;
                f16* lB = Bs + (w * 32 + it * 8) * 64;
                __builtin_amdgcn_global_load_lds((const __attribute__((address_space(1))) void*)gB,
                                                 (__attribute__((address_space(3))) void*)lB, 16, 0, 0);
            }
        } else {
            const f16* A16 = (const f16*)Av;
#pragma unroll
            for (int it = 0; it < 4; ++it) {
                int row = w * 32 + it * 8 + (l >> 3);
                int gchunk = sp ^ (row & 7);
                const f16* gA = A16 + (size_t)(m0 + row) * K + k0 + gchunk * 8;
                const f16* gB = B + (size_t)(n0 + row) * K + k0 + gchunk * 8;
                f16* lA = As + (w * 32 + it * 8) * 64;  // wave-uniform; HW adds lane*16B
                f16* lB = Bs + (w * 32 + it * 8) * 64;
                __builtin_amdgcn_global_load_lds((const __attribute__((address_space(1))) void*)gA,
                                                 (__attribute__((address_space(3))) void*)lA, 16, 0, 0);
                __builtin_amdgcn_global_load_lds((const __attribute__((address_space(1))) void*)gB,
                                                 (__attribute__((address_space(3))) void*)lB, 16, 0, 0);
            }
        }
        __syncthreads();
#pragma unroll
        for (int ks = 0; ks < 2; ++ks) {
            f16x8 af[4], bfr[4];
#pragma unroll
            for (int mi = 0; mi < 4; ++mi) {
                int r = 64 * wm + 16 * mi + lr;
                int chunk = (lg + 4 * ks) ^ (r & 7);
                af[mi] = *(const f16x8*)(As + r * 64 + chunk * 8);
            }
#pragma unroll
            for (int ni = 0; ni < 4; ++ni) {
                int r = 64 * wn + 16 * ni + lr;
                int chunk = (lg + 4 * ks) ^ (r & 7);
                bfr[ni] = *(const f16x8*)(Bs + r * 64 + chunk * 8);
            }
            __builtin_amdgcn_s_setprio(1);
#pragma unroll
            for (int mi = 0; mi < 4; ++mi)
#pragma unroll
                for (int ni = 0; ni < 4; ++ni)
                    acc[mi][ni] = MFMA16(af[mi], bfr[ni], acc[mi][ni]);
            __builtin_amdgcn_s_setprio(0);
        }
    }
    // epilogue: C/D layout col=lane&15, row=(lane>>4)*4+reg [m89]
#pragma unroll
    for (int mi = 0; mi < 4; ++mi) {
#pragma unroll
        for (int ni = 0; ni < 4; ++ni) {
            int col = n0 + 64 * wn + 16 * ni + lr;
            float bv = bias[col];
#pragma unroll
            for (int reg = 0; reg < 4; ++reg) {
                int row = m0 + 64 * wm + 16 * mi + 4 * lg + reg;
                C[(size_t)row * N + col] = (OUT_T)(acc[mi][ni][reg] + bv);
            }
        }
    }
}

// ---------------------------------------------------------------------------
// fused attention: R4 internals verbatim, packed 2 independent waves/block
// (each wave owns one (window,head); wave-private P; no cross-wave sync).
// QK^T via MFMA from interleaved qkv, V fragments prefetched into registers
// right after QK^T (T14, hides under softmax), wave-parallel softmax, P
// through wave-private XOR-swizzled LDS, MFMA PV per stream.
// Over-reads (rows past last window / j>=49) stay inside ws; P=0 kills them.
// ---------------------------------------------------------------------------
__global__ __launch_bounds__(128) void attn_kernel(const f16* __restrict__ qkv,
                                                   const f16* __restrict__ vse,
                                                   const float* __restrict__ bm_all,
                                                   f16* __restrict__ att_se, f16* __restrict__ att_de) {
    __shared__ __align__(16) f16 Ps[2][64 * 64];  // per-wave P, swizzled

    const int wv = threadIdx.x >> 6;
    const int l = threadIdx.x & 63;
    const int bh = blockIdx.x * 2 + wv;
    const int b = bh / NHEAD, h = bh - b * NHEAD;
    const int lr = l & 15, lg = l >> 4;
    const size_t wbase = (size_t)b * NTOK;
    f16* P = Ps[wv];

    f16x8 qa[4], kb[4];
#pragma unroll
    for (int mi = 0; mi < 4; ++mi)
        qa[mi] = *(const f16x8*)(qkv + (wbase + 16 * mi + lr) * 1152 + h * 32 + lg * 8);
#pragma unroll
    for (int ni = 0; ni < 4; ++ni)
        kb[ni] = *(const f16x8*)(qkv + (wbase + 16 * ni + lr) * 1152 + 384 + h * 32 + lg * 8);

    const f32x4 zero4 = {0.f, 0.f, 0.f, 0.f};
    f32x4 S[4][4];
    __builtin_amdgcn_s_setprio(1);
#pragma unroll
    for (int mi = 0; mi < 4; ++mi)
#pragma unroll
        for (int ni = 0; ni < 4; ++ni)
            S[mi][ni] = MFMA16(qa[mi], kb[ni], zero4);
    __builtin_amdgcn_s_setprio(0);

    // T14: issue all V-fragment gathers now; they complete under the softmax
    f16x8 vbr[2][2][2];  // [stream][ks][ni]
#pragma unroll
    for (int s = 0; s < 2; ++s) {
        const f16* vbase = s ? (qkv + wbase * 1152 + 768 + h * 32) : (vse + wbase * 384 + h * 32);
        const int RS = s ? 1152 : 384;
#pragma unroll
        for (int ks = 0; ks < 2; ++ks)
#pragma unroll
            for (int ni = 0; ni < 2; ++ni) {
                const f16* p = vbase + (size_t)(8 * lg + 32 * ks) * RS + 16 * ni + lr;
#pragma unroll
                for (int e = 0; e < 8; ++e) vbr[s][ks][ni][e] = p[(size_t)e * RS];
            }
    }

    const float* bmp = bm_all + (size_t)((b & 3) * NHEAD + h) * 4096;
#pragma unroll
    for (int mi = 0; mi < 4; ++mi) {
#pragma unroll
        for (int reg = 0; reg < 4; ++reg) {
            int r = 16 * mi + 4 * lg + reg;
            float v[4];
#pragma unroll
            for (int ni = 0; ni < 4; ++ni)
                v[ni] = S[mi][ni][reg] * SCALE_F + bmp[(r << 6) + 16 * ni + lr];
            float mx = fmaxf(fmaxf(v[0], v[1]), fmaxf(v[2], v[3]));
#pragma unroll
            for (int off = 1; off < 16; off <<= 1) mx = fmaxf(mx, __shfl_xor(mx, off));
            float e[4];
            float sm = 0.f;
#pragma unroll
            for (int ni = 0; ni < 4; ++ni) {
                e[ni] = __expf(v[ni] - mx);
                sm += e[ni];
            }
#pragma unroll
            for (int off = 1; off < 16; off <<= 1) sm += __shfl_xor(sm, off);
            float inv = 1.f / sm;
#pragma unroll
            for (int ni = 0; ni < 4; ++ni)
                P[(r << 6) + ((16 * ni + lr) ^ ((r & 7) << 3))] = (f16)(e[ni] * inv);
        }
    }
    WAITL0();  // wave-private P: per-wave LDS ordering is enough
    SCHEDB();

#pragma unroll
    for (int s = 0; s < 2; ++s) {
        f32x4 o[4][2] = {};
#pragma unroll
        for (int ks = 0; ks < 2; ++ks) {
            f16x8 pa[4];
#pragma unroll
            for (int mi = 0; mi < 4; ++mi) {
                int r = 16 * mi + lr;
                pa[mi] = *(const f16x8*)(P + (r << 6) + ((8 * lg + 32 * ks) ^ ((r & 7) << 3)));
            }
            __builtin_amdgcn_s_setprio(1);
#pragma unroll
            for (int ni = 0; ni < 2; ++ni)
#pragma unroll
                for (int mi = 0; mi < 4; ++mi) o[mi][ni] = MFMA16(pa[mi], vbr[s][ks][ni], o[mi][ni]);
            __builtin_amdgcn_s_setprio(0);
        }
        f16* dst = s ? att_de : att_se;
#pragma unroll
        for (int mi = 0; mi < 4; ++mi) {
#pragma unroll
            for (int reg = 0; reg < 4; ++reg) {
                int r = 16 * mi + 4 * lg + reg;
                if (r < NTOK) {
#pragma unroll
                    for (int ni = 0; ni < 2; ++ni)
                        dst[(wbase + r) * 384 + h * 32 + 16 * ni + lr] = (f16)o[mi][ni][reg];
                }
            }
        }
    }
}

// ---------------------------------------------------------------------------
extern "C" void kernel_launch(void* const* d_in, const int* in_sizes, int n_in,
                              void* d_out, int out_size, void* d_ws, size_t ws_size,
                              hipStream_t stream) {
    const float* se = (const float*)d_in[0];
    const float* de = (const float*)d_in[1];
    const float* mask = (const float*)d_in[2];
    const float* w_v_se = (const float*)d_in[3];
    const float* b_v_se = (const float*)d_in[4];
    const float* w_qkv = (const float*)d_in[5];
    const float* b_qkv = (const float*)d_in[6];
    const float* w_proj_se = (const float*)d_in[7];
    const float* b_proj_se = (const float*)d_in[8];
    const float* w_proj_de = (const float*)d_in[9];
    const float* b_proj_de = (const float*)d_in[10];
    const float* rpb = (const float*)d_in[11];
    const int* rel_idx = (const int*)d_in[12];

    const size_t SE_ELEMS = (size_t)NBW * NTOK * 384;  // 38,535,168

    char* ws = (char*)d_ws;
    f16* att_se = (f16*)(ws);                 // (100352, 384) f16
    f16* att_de = (f16*)(ws + 77070336);      // (100352, 384) f16
    f16* qkv_h = (f16*)(ws + 154140672);      // (100352, 1152) f16
    f16* vse_h = (f16*)(ws + 385351680);      // (100352, 384) f16
    f16* wqkv_h = (f16*)(ws + 462422016);
    f16* wvse_h = (f16*)(ws + 463306752);
    f16* wpse_h = (f16*)(ws + 463601664);
    f16* wpde_h = (f16*)(ws + 463896576);
    float* bm = (float*)(ws + 464191488);

    cast_weights<<<864, 256, 0, stream>>>(w_qkv, w_v_se, w_proj_se, w_proj_de,
                                          wqkv_h, wvse_h, wpse_h, wpde_h);
    prep_bm<<<48, 64, 0, stream>>>(rpb, rel_idx, mask, bm);

    // qkv = de @ w_qkv^T + b   (M=100352, N=1152, K=384), A read as f32 (fused cast)
    gemm_bt<f16, true><<<dim3(9, 784), 256, 0, stream>>>((const void*)de, wqkv_h, b_qkv, qkv_h, 100352, 1152, 384);
    // v_se = se @ w_v_se^T + b (M=100352, N=384, K=384), A read as f32 (fused cast)
    gemm_bt<f16, true><<<dim3(3, 784), 256, 0, stream>>>((const void*)se, wvse_h, b_v_se, vse_h, 100352, 384, 384);

    // attention: 2 (window,head) pairs per block
    attn_kernel<<<NBW * NHEAD / 2, 128, 0, stream>>>(qkv_h, vse_h, bm, att_se, att_de);

    // projections straight into d_out (f32); A is f16 -> global_load_lds path
    gemm_bt<float, false><<<dim3(3, 784), 256, 0, stream>>>((const void*)att_se, wpse_h, b_proj_se, (float*)d_out,
                                                            100352, 384, 384);
    gemm_bt<float, false><<<dim3(3, 784), 256, 0, stream>>>((const void*)att_de, wpde_h, b_proj_de,
                                                            (float*)d_out + SE_ELEMS, 100352, 384, 384);
}